// Round 16
// baseline (530.429 us; speedup 1.0000x reference)
//
#include <hip/hip_runtime.h>
#include <math.h>

typedef unsigned short u16;
typedef unsigned int u32;
typedef __attribute__((ext_vector_type(4))) short s4v;
typedef __attribute__((ext_vector_type(8))) short s8v;
typedef __attribute__((ext_vector_type(4))) float f4v;

constexpr int Bn = 4;
constexpr int Ln = 2048;
constexpr int En = 1024;
constexpr int Hn = 16;
constexpr int Dn = 64;
constexpr int Mn = Bn * Ln;      // 8192
constexpr int QKV_N = 3 * En;    // 3072

constexpr float QSCALE_F = 0.04511175463f;   // log2(e)/32: folds softmax 1/sqrt(E) + exp->exp2

__device__ inline u16 f2bf(float f) {            // fp32 -> bf16, round-nearest-even
    union { float f; unsigned u; } v; v.f = f;
    unsigned r = v.u + 0x7FFFu + ((v.u >> 16) & 1u);
    return (u16)(r >> 16);
}
// packed RNE bf16 convert: lo -> bits[15:0], hi -> bits[31:16]
__device__ inline u32 cvtpk(float lo, float hi) {
    u32 r;
    asm("v_cvt_pk_bf16_f32 %0, %1, %2" : "=v"(r) : "v"(lo), "v"(hi));
    return r;
}
__device__ inline s8v cat(s4v a, s4v b) {
    s8v r;
    r[0]=a[0]; r[1]=a[1]; r[2]=a[2]; r[3]=a[3];
    r[4]=b[0]; r[5]=b[1]; r[6]=b[2]; r[7]=b[3];
    return r;
}
// MFMA A/B fragment for 16x16x32, padded-LDS form: elems 0-3 at k=lg*4+j, 4-7 at +16
__device__ inline s8v ldfrag(const u16* p) {
    s4v a = *(const s4v*)p;
    s4v b = *(const s4v*)(p + 16);
    return cat(a, b);
}
// async global->LDS, 16B per lane, wave-uniform LDS base
__device__ inline void gload_lds16(const u16* g, u16* l) {
    __builtin_amdgcn_global_load_lds(
        (const __attribute__((address_space(1))) void*)g,
        (__attribute__((address_space(3))) void*)l, 16, 0, 0);
}

// ---------------- x fp32 -> bf16 (vectorized, one thread per 8 elems) ------------------
__global__ __launch_bounds__(256) void cvt_bf16(
    const float* __restrict__ in, u16* __restrict__ outp, int n8)
{
    const int i = blockIdx.x * 256 + threadIdx.x;
    if (i >= n8) return;
    float4 f0 = *(const float4*)(in + (size_t)i * 8);
    float4 f1 = *(const float4*)(in + (size_t)i * 8 + 4);
    s8v v;
    v[0] = (short)f2bf(f0.x); v[1] = (short)f2bf(f0.y);
    v[2] = (short)f2bf(f0.z); v[3] = (short)f2bf(f0.w);
    v[4] = (short)f2bf(f1.x); v[5] = (short)f2bf(f1.y);
    v[6] = (short)f2bf(f1.z); v[7] = (short)f2bf(f1.w);
    *(s8v*)&outp[(size_t)i * 8] = v;
}

// ---------------- weight transpose+convert: W[K][N] fp32 -> T[N][K] bf16 --------------
__global__ __launch_bounds__(256) void transT(
    const float* __restrict__ W, int K, int N, u16* __restrict__ T)
{
    __shared__ float tile[64][65];
    const int t  = threadIdx.x;
    const int kb = blockIdx.y * 64;
    const int nb = blockIdx.x * 64;
    const int r  = t >> 2;
    const int c4 = (t & 3) * 16;

    const float* wp = W + (size_t)(kb + r) * N + nb + c4;
    #pragma unroll
    for (int i = 0; i < 4; ++i) {
        float4 v = *(const float4*)(wp + 4 * i);
        tile[r][c4 + 4 * i + 0] = v.x; tile[r][c4 + 4 * i + 1] = v.y;
        tile[r][c4 + 4 * i + 2] = v.z; tile[r][c4 + 4 * i + 3] = v.w;
    }
    __syncthreads();

    s8v hv[2];
    #pragma unroll
    for (int c = 0; c < 2; ++c)
        #pragma unroll
        for (int j = 0; j < 8; ++j)
            hv[c][j] = (short)f2bf(tile[c4 + c * 8 + j][r]);
    u16* th = T + (size_t)(nb + r) * K + kb + c4;
    *(s8v*)th = hv[0]; *(s8v*)(th + 8) = hv[1];
}

// -------- bf16 MFMA GEMM, m97 structure: 128x128 tile, BK=32, linear LDS, ------------
// global_load_lds w16 staging, single ds_read_b128 per fragment (k-chunk order;
// A and B share the same per-lane k permutation so MFMA's 32-slot dot is exact).
// QPRE: scale output cols < En by QSCALE_F before the bf16 round (Q prescale).
template <bool OUT_BF16, bool QPRE>
__global__ __launch_bounds__(256) void gemm_bf16(
    const u16* __restrict__ A, int lda,
    const u16* __restrict__ BT, int ldb,
    float* __restrict__ C, u16* __restrict__ Cb, int ldc,
    const float* __restrict__ bias, int K)
{
    __shared__ __align__(16) u16 As[128 * 32];   // 8 KiB, linear [row][32k]
    __shared__ __align__(16) u16 Bs[128 * 32];   // 8 KiB

    const int t    = threadIdx.x;
    const int lane = t & 63;
    const int w    = t >> 6;
    const int l15  = lane & 15;
    const int lg   = lane >> 4;
    const int wr   = w >> 1;              // 0..1
    const int wc   = w & 1;               // 0..1
    const int m0   = blockIdx.y * 128;
    const int n0   = blockIdx.x * 128;

    f4v acc[4][4];
    #pragma unroll
    for (int m = 0; m < 4; ++m)
        #pragma unroll
        for (int n = 0; n < 4; ++n) acc[m][n] = (f4v){0.f, 0.f, 0.f, 0.f};

    for (int k0 = 0; k0 < K; k0 += 32) {
        __syncthreads();                  // prev iter frag reads complete
        // stage A and B tiles: slot s (16B) = row s>>2, k-chunk s&3
        #pragma unroll
        for (int i = 0; i < 2; ++i) {
            const int s   = i * 256 + t;          // per-lane slot
            const int ub  = (i * 256 + w * 64) * 8; // wave-uniform LDS base (u16)
            const int row = s >> 2, ch = s & 3;
            gload_lds16(A  + (size_t)(m0 + row) * lda + k0 + ch * 8, As + ub);
            gload_lds16(BT + (size_t)(n0 + row) * ldb + k0 + ch * 8, Bs + ub);
        }
        __syncthreads();                  // drains vmcnt: tiles staged

        s8v fa[4], fb[4];
        #pragma unroll
        for (int m = 0; m < 4; ++m)
            fa[m] = *(const s8v*)&As[(wr * 64 + m * 16 + l15) * 32 + lg * 8];
        #pragma unroll
        for (int n = 0; n < 4; ++n)
            fb[n] = *(const s8v*)&Bs[(wc * 64 + n * 16 + l15) * 32 + lg * 8];
        #pragma unroll
        for (int m = 0; m < 4; ++m)
            #pragma unroll
            for (int n = 0; n < 4; ++n)
                acc[m][n] = __builtin_amdgcn_mfma_f32_16x16x32_bf16(fa[m], fb[n], acc[m][n], 0, 0, 0);
    }

    if (OUT_BF16) {
        #pragma unroll
        for (int m = 0; m < 4; ++m)
            #pragma unroll
            for (int n = 0; n < 4; ++n) {
                const int col = n0 + wc * 64 + n * 16 + l15;
                const float sc = (QPRE && col < En) ? QSCALE_F : 1.0f;
                #pragma unroll
                for (int r = 0; r < 4; ++r) {
                    const size_t row = m0 + wr * 64 + m * 16 + lg * 4 + r;
                    Cb[row * ldc + col] = f2bf(acc[m][n][r] * sc);
                }
            }
    } else {
        #pragma unroll
        for (int n = 0; n < 4; ++n) {
            const int col = n0 + wc * 64 + n * 16 + l15;
            const float bv = bias[col];
            #pragma unroll
            for (int m = 0; m < 4; ++m)
                #pragma unroll
                for (int r = 0; r < 4; ++r) {
                    const size_t row = m0 + wr * 64 + m * 16 + lg * 4 + r;
                    C[row * ldc + col] = acc[m][n][r] + bv;
                }
        }
    }
}

// ---------------- bf16 MFMA flash attention v13: R12 structure + KV-split-2 -----------
// Per-wave inner code = R12 (measured best 89.3us). Each (bh, q0) is computed by TWO
// blocks (blockIdx.z = split), each over half the KV range (16 tiles). Fixed-max
// softmax => partials combine exactly: O = O0+O1 (unnormalized), l = l0+l1.
// Grid 64 x 8 x 2 = 1024 blocks = 4/CU = 32 waves/CU (2x R12's TLP; kernel was
// latency-bound with all pipes <50%). Writes fp32 partial O and l; combine kernel
// normalizes into the qkv Q region. K staged by waves 0-3, V by waves 4-7.
// Pad-68: conflict-free frag reads. launch_bounds(512,8) pins VGPR<=64 (R12 used 60).
__global__ __launch_bounds__(512, 8) void flash_bf16(
    const u16* __restrict__ qkv,
    float* __restrict__ P0, float* __restrict__ P1, float* __restrict__ lout)
{
    __shared__ __align__(16) u16 lds[8704];   // 17 KiB
    u16* Ks = lds;                            // [64 kv][68 d]
    u16* Vt = lds + 4352;                     // [64 d][68 kv]

    const int t    = threadIdx.x;
    const int lane = t & 63;
    const int w    = t >> 6;                  // 0..7
    const int l15  = lane & 15;
    const int lg   = lane >> 4;

    const int bh    = blockIdx.x;
    const int b     = bh >> 4;
    const int h     = bh & 15;
    const int q0    = blockIdx.y * 256;
    const int split = blockIdx.z;             // 0 or 1: kv half

    const size_t rowB = (size_t)b * Ln;
    float* __restrict__ Pout = split ? P1 : P0;

    // Q fragments (B-operand: lane l15 = q row) in registers for the whole kernel
    s8v qf[2][2];
    #pragma unroll
    for (int qb = 0; qb < 2; ++qb) {
        const size_t qrow = (rowB + q0 + w * 32 + qb * 16 + l15) * QKV_N + h * Dn;
        qf[qb][0] = ldfrag(qkv + qrow + lg * 4);
        qf[qb][1] = ldfrag(qkv + qrow + 32 + lg * 4);
    }

    f4v o[2][4];
    float lpart[2] = {0.f, 0.f};
    #pragma unroll
    for (int qb = 0; qb < 2; ++qb)
        #pragma unroll
        for (int db = 0; db < 4; ++db) o[qb][db] = (f4v){0.f, 0.f, 0.f, 0.f};

    // staging roles: waves 0-3 stage K, waves 4-7 stage V (32B/thread patterns)
    const bool isK = (w < 4);
    const int t4   = t & 255;                  // index within the 256-thread half
    const int sr   = t4 >> 2;                  // K: kv row 0..63
    const int sc   = (t4 & 3) * 16;            // K: d 0,16,32,48
    const int vr   = (t4 >> 6) * 16 + (t4 & 7) * 2;  // V: kv pair base (even)
    const int vc   = ((t4 >> 3) & 7) * 8;            // V: d chunk 0..56

    const int kbeg = split * (Ln / 2);         // this block's kv half
    const int kend = kbeg + (Ln / 2);

    for (int k0 = kbeg; k0 < kend; k0 += 64) {
        s8v x0, x1;
        if (isK) {   // K: 16+16 d-values of kv row sr
            const size_t krow = (rowB + k0 + sr) * QKV_N + En + h * Dn + sc;
            x0 = *(const s8v*)(qkv + krow);
            x1 = *(const s8v*)(qkv + krow + 8);
        } else {     // V: d-chunk vc of kv rows vr, vr+1
            const u16* vp = qkv + (rowB + k0 + vr) * QKV_N + 2 * En + h * Dn + vc;
            x0 = *(const s8v*)vp;
            x1 = *(const s8v*)(vp + QKV_N);
        }

        __syncthreads();                 // prev tile LDS reads complete
        if (isK) {
            *(s8v*)&Ks[sr * 68 + sc]     = x0;
            *(s8v*)&Ks[sr * 68 + sc + 8] = x1;
        } else {
            #pragma unroll
            for (int i = 0; i < 8; ++i) {    // packed dword store: 16 banks/phase
                u32 dw = (u32)(u16)x0[i] | ((u32)(u16)x1[i] << 16);
                *(u32*)&Vt[(vc + i) * 68 + vr] = dw;
            }
        }
        __syncthreads();                 // tile staged

        // ---- S^T = K Q^T : lane l15 = q, reg r + lg = kv (Q carries log2e/32) ----
        f4v st[2][4];
        __builtin_amdgcn_s_setprio(1);
        #pragma unroll
        for (int c = 0; c < 4; ++c) {
            s8v kf0 = ldfrag(&Ks[(c * 16 + l15) * 68 + lg * 4]);
            s8v kf1 = ldfrag(&Ks[(c * 16 + l15) * 68 + 32 + lg * 4]);
            #pragma unroll
            for (int qb = 0; qb < 2; ++qb) {
                f4v acc = (f4v){0.f, 0.f, 0.f, 0.f};
                acc = __builtin_amdgcn_mfma_f32_16x16x32_bf16(kf0, qf[qb][0], acc, 0, 0, 0);
                acc = __builtin_amdgcn_mfma_f32_16x16x32_bf16(kf1, qf[qb][1], acc, 0, 0, 0);
                st[qb][c] = acc;
            }
        }
        __builtin_amdgcn_s_setprio(0);

        // ---- P = v_exp_f32(S) in-register; RNE pack via v_cvt_pk_bf16_f32 ----
        s8v pa[2][2];
        #pragma unroll
        for (int qb = 0; qb < 2; ++qb) {
            float p[4][4];
            #pragma unroll
            for (int c = 0; c < 4; ++c)
                #pragma unroll
                for (int r = 0; r < 4; ++r)
                    p[c][r] = __builtin_amdgcn_exp2f(st[qb][c][r]);
            float s0 = (p[0][0] + p[0][1]) + (p[0][2] + p[0][3]);
            float s1 = (p[1][0] + p[1][1]) + (p[1][2] + p[1][3]);
            float s2 = (p[2][0] + p[2][1]) + (p[2][2] + p[2][3]);
            float s3 = (p[3][0] + p[3][1]) + (p[3][2] + p[3][3]);
            lpart[qb] += (s0 + s1) + (s2 + s3);
            union { s8v s; u32 u[4]; } a0, a1;
            a0.u[0] = cvtpk(p[0][0], p[0][1]);   // kv slots r=0,1   (c=0)
            a0.u[1] = cvtpk(p[0][2], p[0][3]);
            a0.u[2] = cvtpk(p[1][0], p[1][1]);   // kv 16+ (c=1)
            a0.u[3] = cvtpk(p[1][2], p[1][3]);
            a1.u[0] = cvtpk(p[2][0], p[2][1]);   // kv 32+ (c=2)
            a1.u[1] = cvtpk(p[2][2], p[2][3]);
            a1.u[2] = cvtpk(p[3][0], p[3][1]);   // kv 48+ (c=3)
            a1.u[3] = cvtpk(p[3][2], p[3][3]);
            pa[qb][0] = a0.s;
            pa[qb][1] = a1.s;
        }

        // ---- O += P V : A = pa (lane l15 = q), B = Vt rows d ----
        __builtin_amdgcn_s_setprio(1);
        #pragma unroll
        for (int db = 0; db < 4; ++db) {
            s8v vf0 = ldfrag(&Vt[(db * 16 + l15) * 68 + lg * 4]);
            s8v vf1 = ldfrag(&Vt[(db * 16 + l15) * 68 + 32 + lg * 4]);
            #pragma unroll
            for (int qb = 0; qb < 2; ++qb) {
                f4v acc = o[qb][db];
                acc = __builtin_amdgcn_mfma_f32_16x16x32_bf16(pa[qb][0], vf0, acc, 0, 0, 0);
                acc = __builtin_amdgcn_mfma_f32_16x16x32_bf16(pa[qb][1], vf1, acc, 0, 0, 0);
                o[qb][db] = acc;
            }
        }
        __builtin_amdgcn_s_setprio(0);
    }

    // ---- epilogue: reduce l over lg; write fp32 partial O and l (no normalize) ----
    #pragma unroll
    for (int qb = 0; qb < 2; ++qb) {
        lpart[qb] += __shfl_xor(lpart[qb], 16);
        lpart[qb] += __shfl_xor(lpart[qb], 32);
    }
    if (lg == 0) {
        const size_t lrow = (size_t)split * Mn + rowB + q0 + w * 32;
        lout[(lrow + l15) * Hn + h]      = lpart[0];
        lout[(lrow + 16 + l15) * Hn + h] = lpart[1];
    }
    #pragma unroll
    for (int qb = 0; qb < 2; ++qb)
        #pragma unroll
        for (int db = 0; db < 4; ++db)
            #pragma unroll
            for (int r = 0; r < 4; ++r) {
                const size_t idx =
                    (rowB + q0 + w * 32 + qb * 16 + lg * 4 + r) * En + h * Dn + db * 16 + l15;
                Pout[idx] = o[qb][db][r];
            }
}

// ---------------- combine: O = (P0+P1) / (l0+l1), bf16 into the qkv Q region ----------
__global__ __launch_bounds__(256) void combine(
    const float* __restrict__ P0, const float* __restrict__ P1,
    const float* __restrict__ lbuf, u16* __restrict__ qkv, int n8)
{
    const int i = blockIdx.x * 256 + threadIdx.x;
    if (i >= n8) return;
    const size_t f = (size_t)i * 8;
    const int q   = (int)(f >> 10);       // global row (b*Ln + l)
    const int rem = (int)(f & 1023);      // h*64 + d
    const int h   = rem >> 6;
    const float l0 = lbuf[(size_t)q * Hn + h];
    const float l1 = lbuf[(size_t)Mn * Hn + (size_t)q * Hn + h];
    const float inv = 1.0f / (l0 + l1);
    float4 a0 = *(const float4*)(P0 + f);
    float4 a1 = *(const float4*)(P0 + f + 4);
    float4 b0 = *(const float4*)(P1 + f);
    float4 b1 = *(const float4*)(P1 + f + 4);
    s8v v;
    v[0] = (short)f2bf((a0.x + b0.x) * inv);
    v[1] = (short)f2bf((a0.y + b0.y) * inv);
    v[2] = (short)f2bf((a0.z + b0.z) * inv);
    v[3] = (short)f2bf((a0.w + b0.w) * inv);
    v[4] = (short)f2bf((a1.x + b1.x) * inv);
    v[5] = (short)f2bf((a1.y + b1.y) * inv);
    v[6] = (short)f2bf((a1.z + b1.z) * inv);
    v[7] = (short)f2bf((a1.w + b1.w) * inv);
    *(s8v*)&qkv[(size_t)q * QKV_N + rem] = v;
}

extern "C" void kernel_launch(void* const* d_in, const int* in_sizes, int n_in,
                              void* d_out, int out_size, void* d_ws, size_t ws_size,
                              hipStream_t stream)
{
    const float* x      = (const float*)d_in[0];   // [B,L,E]
    const float* w_qkv  = (const float*)d_in[1];   // [E,3E]
    const float* w_proj = (const float*)d_in[2];   // [E,E]
    const float* b_proj = (const float*)d_in[3];   // [E]
    float* out = (float*)d_out;                    // [B,L,E]

    // workspace layout (126.9 MB total; xb overlays P0head, dead after qkv GEMM):
    u16*   qkv  = (u16*)d_ws;                          // [M,3E] bf16   50.33 MB
    u16*   wqT  = qkv + (size_t)Mn * QKV_N;            // [3E,E] bf16    6.29 MB
    u16*   wpT  = wqT + (size_t)QKV_N * En;            // [E,E]  bf16    2.10 MB
    float* P1   = (float*)(wpT + (size_t)En * En);     // [M,E]  fp32   33.55 MB
    float* lbuf = P1 + (size_t)Mn * En;                // [2,M,H] fp32   1.05 MB
    float* P0   = lbuf + (size_t)2 * Mn * Hn;          // [M,E]  fp32   33.55 MB
    u16*   xb   = (u16*)P0;                            // [M,E]  bf16 (overlay on P0)

    // 0) convert x, transpose+convert weights
    cvt_bf16<<<(Mn * En / 8 + 255) / 256, 256, 0, stream>>>(x, xb, Mn * En / 8);
    transT<<<dim3(QKV_N / 64, En / 64), 256, 0, stream>>>(w_qkv, En, QKV_N, wqT);
    transT<<<dim3(En / 64, En / 64), 256, 0, stream>>>(w_proj, En, En, wpT);

    // 1) qkv = x @ w_qkv  (bf16 out; Q cols prescaled by log2e/32)
    gemm_bf16<true, true><<<dim3(QKV_N / 128, Mn / 128), 256, 0, stream>>>(
        xb, En, wqT, En, nullptr, qkv, QKV_N, nullptr, En);

    // 2) flash attention, KV-split-2 -> fp32 partials (P0 overwrites dead xb)
    flash_bf16<<<dim3(Bn * Hn, Ln / 256, 2), 512, 0, stream>>>(qkv, P0, P1, lbuf);

    // 2b) combine partials -> bf16 O over the qkv Q region
    combine<<<(Mn * En / 8 + 255) / 256, 256, 0, stream>>>(
        P0, P1, lbuf, qkv, Mn * En / 8);

    // 3) out = O @ w_proj + b_proj  (fp32 out)
    gemm_bf16<false, false><<<dim3(En / 128, Mn / 128), 256, 0, stream>>>(
        qkv, QKV_N, wpT, En, out, nullptr, En, b_proj, En);
}

// Round 17
// 213.786 us; speedup vs baseline: 2.4811x; 2.4811x over previous
//
#include <hip/hip_runtime.h>
#include <math.h>

typedef unsigned short u16;
typedef unsigned int u32;
typedef __attribute__((ext_vector_type(4))) short s4v;
typedef __attribute__((ext_vector_type(8))) short s8v;
typedef __attribute__((ext_vector_type(4))) float f4v;

constexpr int Bn = 4;
constexpr int Ln = 2048;
constexpr int En = 1024;
constexpr int Hn = 16;
constexpr int Dn = 64;
constexpr int Mn = Bn * Ln;      // 8192
constexpr int QKV_N = 3 * En;    // 3072

constexpr float QSCALE_F = 0.04511175463f;   // log2(e)/32: folds softmax 1/sqrt(E) + exp->exp2

__device__ inline u16 f2bf(float f) {            // fp32 -> bf16, round-nearest-even
    union { float f; unsigned u; } v; v.f = f;
    unsigned r = v.u + 0x7FFFu + ((v.u >> 16) & 1u);
    return (u16)(r >> 16);
}
// packed RNE bf16 convert: lo -> bits[15:0], hi -> bits[31:16]
__device__ inline u32 cvtpk(float lo, float hi) {
    u32 r;
    asm("v_cvt_pk_bf16_f32 %0, %1, %2" : "=v"(r) : "v"(lo), "v"(hi));
    return r;
}
__device__ inline s8v cat(s4v a, s4v b) {
    s8v r;
    r[0]=a[0]; r[1]=a[1]; r[2]=a[2]; r[3]=a[3];
    r[4]=b[0]; r[5]=b[1]; r[6]=b[2]; r[7]=b[3];
    return r;
}
// MFMA A/B fragment for 16x16x32, padded-LDS form: elems 0-3 at k=lg*4+j, 4-7 at +16
__device__ inline s8v ldfrag(const u16* p) {
    s4v a = *(const s4v*)p;
    s4v b = *(const s4v*)(p + 16);
    return cat(a, b);
}
// async global->LDS, 16B per lane, wave-uniform LDS base
__device__ inline void gload_lds16(const u16* g, u16* l) {
    __builtin_amdgcn_global_load_lds(
        (const __attribute__((address_space(1))) void*)g,
        (__attribute__((address_space(3))) void*)l, 16, 0, 0);
}

// ---------------- x fp32 -> bf16 (vectorized, one thread per 8 elems) ------------------
__global__ __launch_bounds__(256) void cvt_bf16(
    const float* __restrict__ in, u16* __restrict__ outp, int n8)
{
    const int i = blockIdx.x * 256 + threadIdx.x;
    if (i >= n8) return;
    float4 f0 = *(const float4*)(in + (size_t)i * 8);
    float4 f1 = *(const float4*)(in + (size_t)i * 8 + 4);
    s8v v;
    v[0] = (short)f2bf(f0.x); v[1] = (short)f2bf(f0.y);
    v[2] = (short)f2bf(f0.z); v[3] = (short)f2bf(f0.w);
    v[4] = (short)f2bf(f1.x); v[5] = (short)f2bf(f1.y);
    v[6] = (short)f2bf(f1.z); v[7] = (short)f2bf(f1.w);
    *(s8v*)&outp[(size_t)i * 8] = v;
}

// ---------------- weight transpose+convert: W[K][N] fp32 -> T[N][K] bf16 --------------
__global__ __launch_bounds__(256) void transT(
    const float* __restrict__ W, int K, int N, u16* __restrict__ T)
{
    __shared__ float tile[64][65];
    const int t  = threadIdx.x;
    const int kb = blockIdx.y * 64;
    const int nb = blockIdx.x * 64;
    const int r  = t >> 2;
    const int c4 = (t & 3) * 16;

    const float* wp = W + (size_t)(kb + r) * N + nb + c4;
    #pragma unroll
    for (int i = 0; i < 4; ++i) {
        float4 v = *(const float4*)(wp + 4 * i);
        tile[r][c4 + 4 * i + 0] = v.x; tile[r][c4 + 4 * i + 1] = v.y;
        tile[r][c4 + 4 * i + 2] = v.z; tile[r][c4 + 4 * i + 3] = v.w;
    }
    __syncthreads();

    s8v hv[2];
    #pragma unroll
    for (int c = 0; c < 2; ++c)
        #pragma unroll
        for (int j = 0; j < 8; ++j)
            hv[c][j] = (short)f2bf(tile[c4 + c * 8 + j][r]);
    u16* th = T + (size_t)(nb + r) * K + kb + c4;
    *(s8v*)th = hv[0]; *(s8v*)(th + 8) = hv[1];
}

// -------- bf16 MFMA GEMM, m97 structure: 128x128 tile, BK=32, linear LDS, ------------
// global_load_lds w16 staging, single ds_read_b128 per fragment (k-chunk order;
// A and B share the same per-lane k permutation so MFMA's 32-slot dot is exact).
// QPRE: scale output cols < En by QSCALE_F before the bf16 round (Q prescale).
template <bool OUT_BF16, bool QPRE>
__global__ __launch_bounds__(256) void gemm_bf16(
    const u16* __restrict__ A, int lda,
    const u16* __restrict__ BT, int ldb,
    float* __restrict__ C, u16* __restrict__ Cb, int ldc,
    const float* __restrict__ bias, int K)
{
    __shared__ __align__(16) u16 As[128 * 32];   // 8 KiB, linear [row][32k]
    __shared__ __align__(16) u16 Bs[128 * 32];   // 8 KiB

    const int t    = threadIdx.x;
    const int lane = t & 63;
    const int w    = t >> 6;
    const int l15  = lane & 15;
    const int lg   = lane >> 4;
    const int wr   = w >> 1;              // 0..1
    const int wc   = w & 1;               // 0..1
    const int m0   = blockIdx.y * 128;
    const int n0   = blockIdx.x * 128;

    f4v acc[4][4];
    #pragma unroll
    for (int m = 0; m < 4; ++m)
        #pragma unroll
        for (int n = 0; n < 4; ++n) acc[m][n] = (f4v){0.f, 0.f, 0.f, 0.f};

    for (int k0 = 0; k0 < K; k0 += 32) {
        __syncthreads();                  // prev iter frag reads complete
        // stage A and B tiles: slot s (16B) = row s>>2, k-chunk s&3
        #pragma unroll
        for (int i = 0; i < 2; ++i) {
            const int s   = i * 256 + t;          // per-lane slot
            const int ub  = (i * 256 + w * 64) * 8; // wave-uniform LDS base (u16)
            const int row = s >> 2, ch = s & 3;
            gload_lds16(A  + (size_t)(m0 + row) * lda + k0 + ch * 8, As + ub);
            gload_lds16(BT + (size_t)(n0 + row) * ldb + k0 + ch * 8, Bs + ub);
        }
        __syncthreads();                  // drains vmcnt: tiles staged

        s8v fa[4], fb[4];
        #pragma unroll
        for (int m = 0; m < 4; ++m)
            fa[m] = *(const s8v*)&As[(wr * 64 + m * 16 + l15) * 32 + lg * 8];
        #pragma unroll
        for (int n = 0; n < 4; ++n)
            fb[n] = *(const s8v*)&Bs[(wc * 64 + n * 16 + l15) * 32 + lg * 8];
        #pragma unroll
        for (int m = 0; m < 4; ++m)
            #pragma unroll
            for (int n = 0; n < 4; ++n)
                acc[m][n] = __builtin_amdgcn_mfma_f32_16x16x32_bf16(fa[m], fb[n], acc[m][n], 0, 0, 0);
    }

    if (OUT_BF16) {
        #pragma unroll
        for (int m = 0; m < 4; ++m)
            #pragma unroll
            for (int n = 0; n < 4; ++n) {
                const int col = n0 + wc * 64 + n * 16 + l15;
                const float sc = (QPRE && col < En) ? QSCALE_F : 1.0f;
                #pragma unroll
                for (int r = 0; r < 4; ++r) {
                    const size_t row = m0 + wr * 64 + m * 16 + lg * 4 + r;
                    Cb[row * ldc + col] = f2bf(acc[m][n][r] * sc);
                }
            }
    } else {
        #pragma unroll
        for (int n = 0; n < 4; ++n) {
            const int col = n0 + wc * 64 + n * 16 + l15;
            const float bv = bias[col];
            #pragma unroll
            for (int m = 0; m < 4; ++m)
                #pragma unroll
                for (int r = 0; r < 4; ++r) {
                    const size_t row = m0 + wr * 64 + m * 16 + lg * 4 + r;
                    C[row * ldc + col] = acc[m][n][r] + bv;
                }
        }
    }
}

// ---------------- bf16 MFMA flash attention v14: KV-split-2, NO occupancy pin ---------
// R16's launch_bounds(512,8) forced VGPR=32 -> scratch spill disaster (FETCH 775MB).
// Identical kernel with plain launch_bounds(512): VGPR ~60 (R12-proven), 4 blocks/CU
// fit naturally (2048/60 >= 32 waves). Grid 64 x 8 x 2 = 1024 blocks = 4/CU.
// Fixed-max softmax => partials combine exactly: O = O0+O1, l = l0+l1.
// K staged by waves 0-3, V by waves 4-7. Pad-68: conflict-free frag reads.
__global__ __launch_bounds__(512) void flash_bf16(
    const u16* __restrict__ qkv,
    float* __restrict__ P0, float* __restrict__ P1, float* __restrict__ lout)
{
    __shared__ __align__(16) u16 lds[8704];   // 17 KiB
    u16* Ks = lds;                            // [64 kv][68 d]
    u16* Vt = lds + 4352;                     // [64 d][68 kv]

    const int t    = threadIdx.x;
    const int lane = t & 63;
    const int w    = t >> 6;                  // 0..7
    const int l15  = lane & 15;
    const int lg   = lane >> 4;

    const int bh    = blockIdx.x;
    const int b     = bh >> 4;
    const int h     = bh & 15;
    const int q0    = blockIdx.y * 256;
    const int split = blockIdx.z;             // 0 or 1: kv half

    const size_t rowB = (size_t)b * Ln;
    float* __restrict__ Pout = split ? P1 : P0;

    // Q fragments (B-operand: lane l15 = q row) in registers for the whole kernel
    s8v qf[2][2];
    #pragma unroll
    for (int qb = 0; qb < 2; ++qb) {
        const size_t qrow = (rowB + q0 + w * 32 + qb * 16 + l15) * QKV_N + h * Dn;
        qf[qb][0] = ldfrag(qkv + qrow + lg * 4);
        qf[qb][1] = ldfrag(qkv + qrow + 32 + lg * 4);
    }

    f4v o[2][4];
    float lpart[2] = {0.f, 0.f};
    #pragma unroll
    for (int qb = 0; qb < 2; ++qb)
        #pragma unroll
        for (int db = 0; db < 4; ++db) o[qb][db] = (f4v){0.f, 0.f, 0.f, 0.f};

    // staging roles: waves 0-3 stage K, waves 4-7 stage V (32B/thread patterns)
    const bool isK = (w < 4);
    const int t4   = t & 255;                  // index within the 256-thread half
    const int sr   = t4 >> 2;                  // K: kv row 0..63
    const int sc   = (t4 & 3) * 16;            // K: d 0,16,32,48
    const int vr   = (t4 >> 6) * 16 + (t4 & 7) * 2;  // V: kv pair base (even)
    const int vc   = ((t4 >> 3) & 7) * 8;            // V: d chunk 0..56

    const int kbeg = split * (Ln / 2);         // this block's kv half
    const int kend = kbeg + (Ln / 2);

    for (int k0 = kbeg; k0 < kend; k0 += 64) {
        s8v x0, x1;
        if (isK) {   // K: 16+16 d-values of kv row sr
            const size_t krow = (rowB + k0 + sr) * QKV_N + En + h * Dn + sc;
            x0 = *(const s8v*)(qkv + krow);
            x1 = *(const s8v*)(qkv + krow + 8);
        } else {     // V: d-chunk vc of kv rows vr, vr+1
            const u16* vp = qkv + (rowB + k0 + vr) * QKV_N + 2 * En + h * Dn + vc;
            x0 = *(const s8v*)vp;
            x1 = *(const s8v*)(vp + QKV_N);
        }

        __syncthreads();                 // prev tile LDS reads complete
        if (isK) {
            *(s8v*)&Ks[sr * 68 + sc]     = x0;
            *(s8v*)&Ks[sr * 68 + sc + 8] = x1;
        } else {
            #pragma unroll
            for (int i = 0; i < 8; ++i) {    // packed dword store: 16 banks/phase
                u32 dw = (u32)(u16)x0[i] | ((u32)(u16)x1[i] << 16);
                *(u32*)&Vt[(vc + i) * 68 + vr] = dw;
            }
        }
        __syncthreads();                 // tile staged

        // ---- S^T = K Q^T : lane l15 = q, reg r + lg = kv (Q carries log2e/32) ----
        f4v st[2][4];
        __builtin_amdgcn_s_setprio(1);
        #pragma unroll
        for (int c = 0; c < 4; ++c) {
            s8v kf0 = ldfrag(&Ks[(c * 16 + l15) * 68 + lg * 4]);
            s8v kf1 = ldfrag(&Ks[(c * 16 + l15) * 68 + 32 + lg * 4]);
            #pragma unroll
            for (int qb = 0; qb < 2; ++qb) {
                f4v acc = (f4v){0.f, 0.f, 0.f, 0.f};
                acc = __builtin_amdgcn_mfma_f32_16x16x32_bf16(kf0, qf[qb][0], acc, 0, 0, 0);
                acc = __builtin_amdgcn_mfma_f32_16x16x32_bf16(kf1, qf[qb][1], acc, 0, 0, 0);
                st[qb][c] = acc;
            }
        }
        __builtin_amdgcn_s_setprio(0);

        // ---- P = v_exp_f32(S) in-register; RNE pack via v_cvt_pk_bf16_f32 ----
        s8v pa[2][2];
        #pragma unroll
        for (int qb = 0; qb < 2; ++qb) {
            float p[4][4];
            #pragma unroll
            for (int c = 0; c < 4; ++c)
                #pragma unroll
                for (int r = 0; r < 4; ++r)
                    p[c][r] = __builtin_amdgcn_exp2f(st[qb][c][r]);
            float s0 = (p[0][0] + p[0][1]) + (p[0][2] + p[0][3]);
            float s1 = (p[1][0] + p[1][1]) + (p[1][2] + p[1][3]);
            float s2 = (p[2][0] + p[2][1]) + (p[2][2] + p[2][3]);
            float s3 = (p[3][0] + p[3][1]) + (p[3][2] + p[3][3]);
            lpart[qb] += (s0 + s1) + (s2 + s3);
            union { s8v s; u32 u[4]; } a0, a1;
            a0.u[0] = cvtpk(p[0][0], p[0][1]);   // kv slots r=0,1   (c=0)
            a0.u[1] = cvtpk(p[0][2], p[0][3]);
            a0.u[2] = cvtpk(p[1][0], p[1][1]);   // kv 16+ (c=1)
            a0.u[3] = cvtpk(p[1][2], p[1][3]);
            a1.u[0] = cvtpk(p[2][0], p[2][1]);   // kv 32+ (c=2)
            a1.u[1] = cvtpk(p[2][2], p[2][3]);
            a1.u[2] = cvtpk(p[3][0], p[3][1]);   // kv 48+ (c=3)
            a1.u[3] = cvtpk(p[3][2], p[3][3]);
            pa[qb][0] = a0.s;
            pa[qb][1] = a1.s;
        }

        // ---- O += P V : A = pa (lane l15 = q), B = Vt rows d ----
        __builtin_amdgcn_s_setprio(1);
        #pragma unroll
        for (int db = 0; db < 4; ++db) {
            s8v vf0 = ldfrag(&Vt[(db * 16 + l15) * 68 + lg * 4]);
            s8v vf1 = ldfrag(&Vt[(db * 16 + l15) * 68 + 32 + lg * 4]);
            #pragma unroll
            for (int qb = 0; qb < 2; ++qb) {
                f4v acc = o[qb][db];
                acc = __builtin_amdgcn_mfma_f32_16x16x32_bf16(pa[qb][0], vf0, acc, 0, 0, 0);
                acc = __builtin_amdgcn_mfma_f32_16x16x32_bf16(pa[qb][1], vf1, acc, 0, 0, 0);
                o[qb][db] = acc;
            }
        }
        __builtin_amdgcn_s_setprio(0);
    }

    // ---- epilogue: reduce l over lg; write fp32 partial O and l (no normalize) ----
    #pragma unroll
    for (int qb = 0; qb < 2; ++qb) {
        lpart[qb] += __shfl_xor(lpart[qb], 16);
        lpart[qb] += __shfl_xor(lpart[qb], 32);
    }
    if (lg == 0) {
        const size_t lrow = (size_t)split * Mn + rowB + q0 + w * 32;
        lout[(lrow + l15) * Hn + h]      = lpart[0];
        lout[(lrow + 16 + l15) * Hn + h] = lpart[1];
    }
    #pragma unroll
    for (int qb = 0; qb < 2; ++qb)
        #pragma unroll
        for (int db = 0; db < 4; ++db)
            #pragma unroll
            for (int r = 0; r < 4; ++r) {
                const size_t idx =
                    (rowB + q0 + w * 32 + qb * 16 + lg * 4 + r) * En + h * Dn + db * 16 + l15;
                Pout[idx] = o[qb][db][r];
            }
}

// ---------------- combine: O = (P0+P1) / (l0+l1), bf16 into the qkv Q region ----------
__global__ __launch_bounds__(256) void combine(
    const float* __restrict__ P0, const float* __restrict__ P1,
    const float* __restrict__ lbuf, u16* __restrict__ qkv, int n8)
{
    const int i = blockIdx.x * 256 + threadIdx.x;
    if (i >= n8) return;
    const size_t f = (size_t)i * 8;
    const int q   = (int)(f >> 10);       // global row (b*Ln + l)
    const int rem = (int)(f & 1023);      // h*64 + d
    const int h   = rem >> 6;
    const float l0 = lbuf[(size_t)q * Hn + h];
    const float l1 = lbuf[(size_t)Mn * Hn + (size_t)q * Hn + h];
    const float inv = 1.0f / (l0 + l1);
    float4 a0 = *(const float4*)(P0 + f);
    float4 a1 = *(const float4*)(P0 + f + 4);
    float4 b0 = *(const float4*)(P1 + f);
    float4 b1 = *(const float4*)(P1 + f + 4);
    s8v v;
    v[0] = (short)f2bf((a0.x + b0.x) * inv);
    v[1] = (short)f2bf((a0.y + b0.y) * inv);
    v[2] = (short)f2bf((a0.z + b0.z) * inv);
    v[3] = (short)f2bf((a0.w + b0.w) * inv);
    v[4] = (short)f2bf((a1.x + b1.x) * inv);
    v[5] = (short)f2bf((a1.y + b1.y) * inv);
    v[6] = (short)f2bf((a1.z + b1.z) * inv);
    v[7] = (short)f2bf((a1.w + b1.w) * inv);
    *(s8v*)&qkv[(size_t)q * QKV_N + rem] = v;
}

extern "C" void kernel_launch(void* const* d_in, const int* in_sizes, int n_in,
                              void* d_out, int out_size, void* d_ws, size_t ws_size,
                              hipStream_t stream)
{
    const float* x      = (const float*)d_in[0];   // [B,L,E]
    const float* w_qkv  = (const float*)d_in[1];   // [E,3E]
    const float* w_proj = (const float*)d_in[2];   // [E,E]
    const float* b_proj = (const float*)d_in[3];   // [E]
    float* out = (float*)d_out;                    // [B,L,E]

    // workspace layout (126.9 MB total; xb overlays P0 head, dead after qkv GEMM):
    u16*   qkv  = (u16*)d_ws;                          // [M,3E] bf16   50.33 MB
    u16*   wqT  = qkv + (size_t)Mn * QKV_N;            // [3E,E] bf16    6.29 MB
    u16*   wpT  = wqT + (size_t)QKV_N * En;            // [E,E]  bf16    2.10 MB
    float* P1   = (float*)(wpT + (size_t)En * En);     // [M,E]  fp32   33.55 MB
    float* lbuf = P1 + (size_t)Mn * En;                // [2,M,H] fp32   1.05 MB
    float* P0   = lbuf + (size_t)2 * Mn * Hn;          // [M,E]  fp32   33.55 MB
    u16*   xb   = (u16*)P0;                            // [M,E]  bf16 (overlay on P0)

    // 0) convert x, transpose+convert weights
    cvt_bf16<<<(Mn * En / 8 + 255) / 256, 256, 0, stream>>>(x, xb, Mn * En / 8);
    transT<<<dim3(QKV_N / 64, En / 64), 256, 0, stream>>>(w_qkv, En, QKV_N, wqT);
    transT<<<dim3(En / 64, En / 64), 256, 0, stream>>>(w_proj, En, En, wpT);

    // 1) qkv = x @ w_qkv  (bf16 out; Q cols prescaled by log2e/32)
    gemm_bf16<true, true><<<dim3(QKV_N / 128, Mn / 128), 256, 0, stream>>>(
        xb, En, wqT, En, nullptr, qkv, QKV_N, nullptr, En);

    // 2) flash attention, KV-split-2 -> fp32 partials (P0 overwrites dead xb)
    flash_bf16<<<dim3(Bn * Hn, Ln / 256, 2), 512, 0, stream>>>(qkv, P0, P1, lbuf);

    // 2b) combine partials -> bf16 O over the qkv Q region
    combine<<<(Mn * En / 8 + 255) / 256, 256, 0, stream>>>(
        P0, P1, lbuf, qkv, Mn * En / 8);

    // 3) out = O @ w_proj + b_proj  (fp32 out)
    gemm_bf16<false, false><<<dim3(En / 128, Mn / 128), 256, 0, stream>>>(
        qkv, QKV_N, wpT, En, out, nullptr, En, b_proj, En);
}

// Round 18
// 191.534 us; speedup vs baseline: 2.7694x; 1.1162x over previous
//
#include <hip/hip_runtime.h>
#include <math.h>

typedef unsigned short u16;
typedef unsigned int u32;
typedef __attribute__((ext_vector_type(4))) short s4v;
typedef __attribute__((ext_vector_type(8))) short s8v;
typedef __attribute__((ext_vector_type(4))) float f4v;

constexpr int Bn = 4;
constexpr int Ln = 2048;
constexpr int En = 1024;
constexpr int Hn = 16;
constexpr int Dn = 64;
constexpr int Mn = Bn * Ln;      // 8192
constexpr int QKV_N = 3 * En;    // 3072

constexpr float QSCALE_F = 0.04511175463f;   // log2(e)/32: folds softmax 1/sqrt(E) + exp->exp2

__device__ inline u16 f2bf(float f) {            // fp32 -> bf16, round-nearest-even
    union { float f; unsigned u; } v; v.f = f;
    unsigned r = v.u + 0x7FFFu + ((v.u >> 16) & 1u);
    return (u16)(r >> 16);
}
// packed RNE bf16 convert: lo -> bits[15:0], hi -> bits[31:16]
__device__ inline u32 cvtpk(float lo, float hi) {
    u32 r;
    asm("v_cvt_pk_bf16_f32 %0, %1, %2" : "=v"(r) : "v"(lo), "v"(hi));
    return r;
}
__device__ inline s8v cat(s4v a, s4v b) {
    s8v r;
    r[0]=a[0]; r[1]=a[1]; r[2]=a[2]; r[3]=a[3];
    r[4]=b[0]; r[5]=b[1]; r[6]=b[2]; r[7]=b[3];
    return r;
}
// MFMA A/B fragment for 16x16x32, padded-LDS form: elems 0-3 at k=lg*4+j, 4-7 at +16
__device__ inline s8v ldfrag(const u16* p) {
    s4v a = *(const s4v*)p;
    s4v b = *(const s4v*)(p + 16);
    return cat(a, b);
}
// async global->LDS, 16B per lane, wave-uniform LDS base
__device__ inline void gload_lds16(const u16* g, u16* l) {
    __builtin_amdgcn_global_load_lds(
        (const __attribute__((address_space(1))) void*)g,
        (__attribute__((address_space(3))) void*)l, 16, 0, 0);
}

// ---------------- fused prep: x->bf16 convert + both weight transposes ----------------
// blocks [0,4096): cvt 8 elems/thread; [4096,4864): w_qkv transT; [4864,5120): w_proj.
__global__ __launch_bounds__(256) void prep(
    const float* __restrict__ x, u16* __restrict__ xb,
    const float* __restrict__ wq, u16* __restrict__ wqT,
    const float* __restrict__ wp, u16* __restrict__ wpT)
{
    __shared__ float tile[64][65];
    const int blk = blockIdx.x;
    const int t   = threadIdx.x;

    if (blk < 4096) {                       // ---- cvt_bf16: 4096*256*8 = Mn*En exact
        const size_t f = ((size_t)blk * 256 + t) * 8;
        float4 f0 = *(const float4*)(x + f);
        float4 f1 = *(const float4*)(x + f + 4);
        s8v v;
        v[0] = (short)f2bf(f0.x); v[1] = (short)f2bf(f0.y);
        v[2] = (short)f2bf(f0.z); v[3] = (short)f2bf(f0.w);
        v[4] = (short)f2bf(f1.x); v[5] = (short)f2bf(f1.y);
        v[6] = (short)f2bf(f1.z); v[7] = (short)f2bf(f1.w);
        *(s8v*)&xb[f] = v;
        return;
    }

    // ---- transT: W[K][N] fp32 -> T[N][K] bf16 (64x64 tiles via LDS) ----
    const float* W; u16* T; int N, local;
    if (blk < 4096 + 768) { W = wq; T = wqT; N = QKV_N; local = blk - 4096; }
    else                  { W = wp; T = wpT; N = En;    local = blk - 4864; }
    const int nbx = N / 64;
    const int kb  = (local / nbx) * 64;
    const int nb  = (local % nbx) * 64;
    const int r   = t >> 2;
    const int c4  = (t & 3) * 16;

    const float* wrow = W + (size_t)(kb + r) * N + nb + c4;
    #pragma unroll
    for (int i = 0; i < 4; ++i) {
        float4 v = *(const float4*)(wrow + 4 * i);
        tile[r][c4 + 4 * i + 0] = v.x; tile[r][c4 + 4 * i + 1] = v.y;
        tile[r][c4 + 4 * i + 2] = v.z; tile[r][c4 + 4 * i + 3] = v.w;
    }
    __syncthreads();

    s8v hv[2];
    #pragma unroll
    for (int c = 0; c < 2; ++c)
        #pragma unroll
        for (int j = 0; j < 8; ++j)
            hv[c][j] = (short)f2bf(tile[c4 + c * 8 + j][r]);
    u16* th = T + (size_t)(nb + r) * En + kb + c4;   // K == En for both weights
    *(s8v*)th = hv[0]; *(s8v*)(th + 8) = hv[1];
}

// -------- bf16 MFMA GEMM, m97 structure + XCD-bijective swizzle (T1) ------------------
// 128x128 tile, BK=32, linear LDS, global_load_lds w16 staging, single ds_read_b128
// per fragment. Work-id swizzle: XCD x executes a CONTIGUOUS chunk of work ids ->
// consecutive work ids share the A-panel -> panel becomes an L2 hit instead of being
// refetched on all 8 XCDs. Requires gridDim.x*gridDim.y % 8 == 0 (1536 / 512: both ok).
// QPRE: scale output cols < En by QSCALE_F before the bf16 round (Q prescale).
template <bool OUT_BF16, bool QPRE>
__global__ __launch_bounds__(256) void gemm_bf16(
    const u16* __restrict__ A, int lda,
    const u16* __restrict__ BT, int ldb,
    float* __restrict__ C, u16* __restrict__ Cb, int ldc,
    const float* __restrict__ bias, int K)
{
    __shared__ __align__(16) u16 As[128 * 32];   // 8 KiB, linear [row][32k]
    __shared__ __align__(16) u16 Bs[128 * 32];   // 8 KiB

    const int t    = threadIdx.x;
    const int lane = t & 63;
    const int w    = t >> 6;
    const int l15  = lane & 15;
    const int lg   = lane >> 4;
    const int wr   = w >> 1;              // 0..1
    const int wc   = w & 1;               // 0..1

    // XCD swizzle: hw id -> work id (bijective, nwg % 8 == 0)
    const int gx  = gridDim.x;
    const int nwg = gx * gridDim.y;
    const int bid = blockIdx.y * gx + blockIdx.x;
    const int swz = (bid & 7) * (nwg >> 3) + (bid >> 3);
    const int m0  = (swz / gx) * 128;
    const int n0  = (swz % gx) * 128;

    f4v acc[4][4];
    #pragma unroll
    for (int m = 0; m < 4; ++m)
        #pragma unroll
        for (int n = 0; n < 4; ++n) acc[m][n] = (f4v){0.f, 0.f, 0.f, 0.f};

    for (int k0 = 0; k0 < K; k0 += 32) {
        __syncthreads();                  // prev iter frag reads complete
        // stage A and B tiles: slot s (16B) = row s>>2, k-chunk s&3
        #pragma unroll
        for (int i = 0; i < 2; ++i) {
            const int s   = i * 256 + t;            // per-lane slot
            const int ub  = (i * 256 + w * 64) * 8; // wave-uniform LDS base (u16)
            const int row = s >> 2, ch = s & 3;
            gload_lds16(A  + (size_t)(m0 + row) * lda + k0 + ch * 8, As + ub);
            gload_lds16(BT + (size_t)(n0 + row) * ldb + k0 + ch * 8, Bs + ub);
        }
        __syncthreads();                  // drains vmcnt: tiles staged

        s8v fa[4], fb[4];
        #pragma unroll
        for (int m = 0; m < 4; ++m)
            fa[m] = *(const s8v*)&As[(wr * 64 + m * 16 + l15) * 32 + lg * 8];
        #pragma unroll
        for (int n = 0; n < 4; ++n)
            fb[n] = *(const s8v*)&Bs[(wc * 64 + n * 16 + l15) * 32 + lg * 8];
        #pragma unroll
        for (int m = 0; m < 4; ++m)
            #pragma unroll
            for (int n = 0; n < 4; ++n)
                acc[m][n] = __builtin_amdgcn_mfma_f32_16x16x32_bf16(fa[m], fb[n], acc[m][n], 0, 0, 0);
    }

    if (OUT_BF16) {
        #pragma unroll
        for (int m = 0; m < 4; ++m)
            #pragma unroll
            for (int n = 0; n < 4; ++n) {
                const int col = n0 + wc * 64 + n * 16 + l15;
                const float sc = (QPRE && col < En) ? QSCALE_F : 1.0f;
                #pragma unroll
                for (int r = 0; r < 4; ++r) {
                    const size_t row = m0 + wr * 64 + m * 16 + lg * 4 + r;
                    Cb[row * ldc + col] = f2bf(acc[m][n][r] * sc);
                }
            }
    } else {
        #pragma unroll
        for (int n = 0; n < 4; ++n) {
            const int col = n0 + wc * 64 + n * 16 + l15;
            const float bv = bias[col];
            #pragma unroll
            for (int m = 0; m < 4; ++m)
                #pragma unroll
                for (int r = 0; r < 4; ++r) {
                    const size_t row = m0 + wr * 64 + m * 16 + lg * 4 + r;
                    C[row * ldc + col] = acc[m][n][r] + bv;
                }
        }
    }
}

// ---------------- bf16 MFMA flash attention (R12-exact, measured best 89.3us) ---------
// 8 waves x 32 q = 256 q/block; grid 64 x 8 = 512 blocks. K staged by waves 0-3,
// V by waves 4-7. Swapped QK^T keeps P in registers; fixed-max softmax (Q prescaled
// by log2e/32 -> P = v_exp_f32(S)); O bf16 in-place over the Q region. Pad-68:
// conflict-free frag reads.
__global__ __launch_bounds__(512) void flash_bf16(u16* __restrict__ qkv)
{
    __shared__ __align__(16) u16 lds[8704];   // 17 KiB
    u16* Ks = lds;                            // [64 kv][68 d]
    u16* Vt = lds + 4352;                     // [64 d][68 kv]

    const int t    = threadIdx.x;
    const int lane = t & 63;
    const int w    = t >> 6;                  // 0..7
    const int l15  = lane & 15;
    const int lg   = lane >> 4;

    const int bh = blockIdx.x;
    const int b  = bh >> 4;
    const int h  = bh & 15;
    const int q0 = blockIdx.y * 256;

    const size_t rowB = (size_t)b * Ln;

    // Q fragments (B-operand: lane l15 = q row) in registers for the whole kernel
    s8v qf[2][2];
    #pragma unroll
    for (int qb = 0; qb < 2; ++qb) {
        const size_t qrow = (rowB + q0 + w * 32 + qb * 16 + l15) * QKV_N + h * Dn;
        qf[qb][0] = ldfrag(qkv + qrow + lg * 4);
        qf[qb][1] = ldfrag(qkv + qrow + 32 + lg * 4);
    }

    f4v o[2][4];
    float lpart[2] = {0.f, 0.f};
    #pragma unroll
    for (int qb = 0; qb < 2; ++qb)
        #pragma unroll
        for (int db = 0; db < 4; ++db) o[qb][db] = (f4v){0.f, 0.f, 0.f, 0.f};

    // staging roles: waves 0-3 stage K, waves 4-7 stage V (32B/thread patterns)
    const bool isK = (w < 4);
    const int t4   = t & 255;                  // index within the 256-thread half
    const int sr   = t4 >> 2;                  // K: kv row 0..63
    const int sc   = (t4 & 3) * 16;            // K: d 0,16,32,48
    const int vr   = (t4 >> 6) * 16 + (t4 & 7) * 2;  // V: kv pair base (even)
    const int vc   = ((t4 >> 3) & 7) * 8;            // V: d chunk 0..56

    for (int k0 = 0; k0 < Ln; k0 += 64) {
        s8v x0, x1;
        if (isK) {   // K: 16+16 d-values of kv row sr
            const size_t krow = (rowB + k0 + sr) * QKV_N + En + h * Dn + sc;
            x0 = *(const s8v*)(qkv + krow);
            x1 = *(const s8v*)(qkv + krow + 8);
        } else {     // V: d-chunk vc of kv rows vr, vr+1
            const u16* vp = qkv + (rowB + k0 + vr) * QKV_N + 2 * En + h * Dn + vc;
            x0 = *(const s8v*)vp;
            x1 = *(const s8v*)(vp + QKV_N);
        }

        __syncthreads();                 // prev tile LDS reads complete
        if (isK) {
            *(s8v*)&Ks[sr * 68 + sc]     = x0;
            *(s8v*)&Ks[sr * 68 + sc + 8] = x1;
        } else {
            #pragma unroll
            for (int i = 0; i < 8; ++i) {    // packed dword store: 16 banks/phase
                u32 dw = (u32)(u16)x0[i] | ((u32)(u16)x1[i] << 16);
                *(u32*)&Vt[(vc + i) * 68 + vr] = dw;
            }
        }
        __syncthreads();                 // tile staged

        // ---- S^T = K Q^T : lane l15 = q, reg r + lg = kv (Q carries log2e/32) ----
        f4v st[2][4];
        __builtin_amdgcn_s_setprio(1);
        #pragma unroll
        for (int c = 0; c < 4; ++c) {
            s8v kf0 = ldfrag(&Ks[(c * 16 + l15) * 68 + lg * 4]);
            s8v kf1 = ldfrag(&Ks[(c * 16 + l15) * 68 + 32 + lg * 4]);
            #pragma unroll
            for (int qb = 0; qb < 2; ++qb) {
                f4v acc = (f4v){0.f, 0.f, 0.f, 0.f};
                acc = __builtin_amdgcn_mfma_f32_16x16x32_bf16(kf0, qf[qb][0], acc, 0, 0, 0);
                acc = __builtin_amdgcn_mfma_f32_16x16x32_bf16(kf1, qf[qb][1], acc, 0, 0, 0);
                st[qb][c] = acc;
            }
        }
        __builtin_amdgcn_s_setprio(0);

        // ---- P = v_exp_f32(S) in-register; RNE pack via v_cvt_pk_bf16_f32 ----
        s8v pa[2][2];
        #pragma unroll
        for (int qb = 0; qb < 2; ++qb) {
            float p[4][4];
            #pragma unroll
            for (int c = 0; c < 4; ++c)
                #pragma unroll
                for (int r = 0; r < 4; ++r)
                    p[c][r] = __builtin_amdgcn_exp2f(st[qb][c][r]);
            float s0 = (p[0][0] + p[0][1]) + (p[0][2] + p[0][3]);
            float s1 = (p[1][0] + p[1][1]) + (p[1][2] + p[1][3]);
            float s2 = (p[2][0] + p[2][1]) + (p[2][2] + p[2][3]);
            float s3 = (p[3][0] + p[3][1]) + (p[3][2] + p[3][3]);
            lpart[qb] += (s0 + s1) + (s2 + s3);
            union { s8v s; u32 u[4]; } a0, a1;
            a0.u[0] = cvtpk(p[0][0], p[0][1]);   // kv slots r=0,1   (c=0)
            a0.u[1] = cvtpk(p[0][2], p[0][3]);
            a0.u[2] = cvtpk(p[1][0], p[1][1]);   // kv 16+ (c=1)
            a0.u[3] = cvtpk(p[1][2], p[1][3]);
            a1.u[0] = cvtpk(p[2][0], p[2][1]);   // kv 32+ (c=2)
            a1.u[1] = cvtpk(p[2][2], p[2][3]);
            a1.u[2] = cvtpk(p[3][0], p[3][1]);   // kv 48+ (c=3)
            a1.u[3] = cvtpk(p[3][2], p[3][3]);
            pa[qb][0] = a0.s;
            pa[qb][1] = a1.s;
        }

        // ---- O += P V : A = pa (lane l15 = q), B = Vt rows d ----
        __builtin_amdgcn_s_setprio(1);
        #pragma unroll
        for (int db = 0; db < 4; ++db) {
            s8v vf0 = ldfrag(&Vt[(db * 16 + l15) * 68 + lg * 4]);
            s8v vf1 = ldfrag(&Vt[(db * 16 + l15) * 68 + 32 + lg * 4]);
            #pragma unroll
            for (int qb = 0; qb < 2; ++qb) {
                f4v acc = o[qb][db];
                acc = __builtin_amdgcn_mfma_f32_16x16x32_bf16(pa[qb][0], vf0, acc, 0, 0, 0);
                acc = __builtin_amdgcn_mfma_f32_16x16x32_bf16(pa[qb][1], vf1, acc, 0, 0, 0);
                o[qb][db] = acc;
            }
        }
        __builtin_amdgcn_s_setprio(0);
    }

    // ---- row-sums: lane(l15=q, lg) holds partial over its kv slots; reduce over lg ----
    #pragma unroll
    for (int qb = 0; qb < 2; ++qb) {
        lpart[qb] += __shfl_xor(lpart[qb], 16);
        lpart[qb] += __shfl_xor(lpart[qb], 32);
    }
    __syncthreads();                     // all waves done with K/V LDS reads
    float* sred = (float*)lds;           // [256] row-sums, q-indexed
    if (lg == 0) {
        sred[w * 32 + l15]      = lpart[0];
        sred[w * 32 + 16 + l15] = lpart[1];
    }
    __syncthreads();

    // ---- normalize and write O bf16 over the Q region (q = lg*4+r rows) ----
    #pragma unroll
    for (int qb = 0; qb < 2; ++qb) {
        float inv[4];
        #pragma unroll
        for (int r = 0; r < 4; ++r)
            inv[r] = 1.0f / sred[w * 32 + qb * 16 + lg * 4 + r];
        #pragma unroll
        for (int db = 0; db < 4; ++db)
            #pragma unroll
            for (int r = 0; r < 4; ++r) {
                const size_t idx =
                    (rowB + q0 + w * 32 + qb * 16 + lg * 4 + r) * QKV_N + h * Dn + db * 16 + l15;
                qkv[idx] = f2bf(o[qb][db][r] * inv[r]);
            }
    }
}

extern "C" void kernel_launch(void* const* d_in, const int* in_sizes, int n_in,
                              void* d_out, int out_size, void* d_ws, size_t ws_size,
                              hipStream_t stream)
{
    const float* x      = (const float*)d_in[0];   // [B,L,E]
    const float* w_qkv  = (const float*)d_in[1];   // [E,3E]
    const float* w_proj = (const float*)d_in[2];   // [E,E]
    const float* b_proj = (const float*)d_in[3];   // [E]
    float* out = (float*)d_out;                    // [B,L,E]

    u16* xb  = (u16*)d_ws;                         // [M,E]   16.8 MB
    u16* qkv = xb  + (size_t)Mn * En;              // [M,3E]  50.3 MB
    u16* wqT = qkv + (size_t)Mn * QKV_N;           // [3E,E]   6.3 MB
    u16* wpT = wqT + (size_t)QKV_N * En;           // [E,E]    2.1 MB

    // 0) fused prep: convert x, transpose+convert both weights (one launch)
    prep<<<5120, 256, 0, stream>>>(x, xb, w_qkv, wqT, w_proj, wpT);

    // 1) qkv = x @ w_qkv  (bf16 out; Q cols prescaled by log2e/32; XCD swizzle)
    gemm_bf16<true, true><<<dim3(QKV_N / 128, Mn / 128), 256, 0, stream>>>(
        xb, En, wqT, En, nullptr, qkv, QKV_N, nullptr, En);

    // 2) flash attention; O written bf16 over the Q region (R12-exact)
    flash_bf16<<<dim3(Bn * Hn, Ln / 256), 512, 0, stream>>>(qkv);

    // 3) out = O @ w_proj + b_proj  (fp32 out; XCD swizzle)
    gemm_bf16<false, false><<<dim3(En / 128, Mn / 128), 256, 0, stream>>>(
        qkv, QKV_N, wpT, En, out, nullptr, En, b_proj, En);
}

// Round 19
// 175.319 us; speedup vs baseline: 3.0255x; 1.0925x over previous
//
#include <hip/hip_runtime.h>
#include <math.h>

typedef unsigned short u16;
typedef unsigned int u32;
typedef __attribute__((ext_vector_type(4))) short s4v;
typedef __attribute__((ext_vector_type(8))) short s8v;
typedef __attribute__((ext_vector_type(4))) float f4v;

constexpr int Bn = 4;
constexpr int Ln = 2048;
constexpr int En = 1024;
constexpr int Hn = 16;
constexpr int Dn = 64;
constexpr int Mn = Bn * Ln;      // 8192
constexpr int QKV_N = 3 * En;    // 3072

constexpr float QSCALE_F = 0.04511175463f;   // log2(e)/32: folds softmax 1/sqrt(E) + exp->exp2

__device__ inline u16 f2bf(float f) {            // fp32 -> bf16, round-nearest-even
    union { float f; unsigned u; } v; v.f = f;
    unsigned r = v.u + 0x7FFFu + ((v.u >> 16) & 1u);
    return (u16)(r >> 16);
}
// packed RNE bf16 convert: lo -> bits[15:0], hi -> bits[31:16]
__device__ inline u32 cvtpk(float lo, float hi) {
    u32 r;
    asm("v_cvt_pk_bf16_f32 %0, %1, %2" : "=v"(r) : "v"(lo), "v"(hi));
    return r;
}
__device__ inline s8v cat(s4v a, s4v b) {
    s8v r;
    r[0]=a[0]; r[1]=a[1]; r[2]=a[2]; r[3]=a[3];
    r[4]=b[0]; r[5]=b[1]; r[6]=b[2]; r[7]=b[3];
    return r;
}
// MFMA A/B fragment for 16x16x32, padded-LDS form: elems 0-3 at k=lg*4+j, 4-7 at +16
__device__ inline s8v ldfrag(const u16* p) {
    s4v a = *(const s4v*)p;
    s4v b = *(const s4v*)(p + 16);
    return cat(a, b);
}
// async global->LDS, 16B per lane, wave-uniform LDS base
__device__ inline void gload_lds16(const u16* g, u16* l) {
    __builtin_amdgcn_global_load_lds(
        (const __attribute__((address_space(1))) void*)g,
        (__attribute__((address_space(3))) void*)l, 16, 0, 0);
}

// ---------------- fused prep: x->bf16 convert + both weight transposes ----------------
// blocks [0,4096): cvt 8 elems/thread; [4096,4864): w_qkv transT; [4864,5120): w_proj.
__global__ __launch_bounds__(256) void prep(
    const float* __restrict__ x, u16* __restrict__ xb,
    const float* __restrict__ wq, u16* __restrict__ wqT,
    const float* __restrict__ wp, u16* __restrict__ wpT)
{
    __shared__ float tile[64][65];
    const int blk = blockIdx.x;
    const int t   = threadIdx.x;

    if (blk < 4096) {                       // ---- cvt_bf16: 4096*256*8 = Mn*En exact
        const size_t f = ((size_t)blk * 256 + t) * 8;
        float4 f0 = *(const float4*)(x + f);
        float4 f1 = *(const float4*)(x + f + 4);
        s8v v;
        v[0] = (short)f2bf(f0.x); v[1] = (short)f2bf(f0.y);
        v[2] = (short)f2bf(f0.z); v[3] = (short)f2bf(f0.w);
        v[4] = (short)f2bf(f1.x); v[5] = (short)f2bf(f1.y);
        v[6] = (short)f2bf(f1.z); v[7] = (short)f2bf(f1.w);
        *(s8v*)&xb[f] = v;
        return;
    }

    // ---- transT: W[K][N] fp32 -> T[N][K] bf16 (64x64 tiles via LDS) ----
    const float* W; u16* T; int N, local;
    if (blk < 4096 + 768) { W = wq; T = wqT; N = QKV_N; local = blk - 4096; }
    else                  { W = wp; T = wpT; N = En;    local = blk - 4864; }
    const int nbx = N / 64;
    const int kb  = (local / nbx) * 64;
    const int nb  = (local % nbx) * 64;
    const int r   = t >> 2;
    const int c4  = (t & 3) * 16;

    const float* wrow = W + (size_t)(kb + r) * N + nb + c4;
    #pragma unroll
    for (int i = 0; i < 4; ++i) {
        float4 v = *(const float4*)(wrow + 4 * i);
        tile[r][c4 + 4 * i + 0] = v.x; tile[r][c4 + 4 * i + 1] = v.y;
        tile[r][c4 + 4 * i + 2] = v.z; tile[r][c4 + 4 * i + 3] = v.w;
    }
    __syncthreads();

    s8v hv[2];
    #pragma unroll
    for (int c = 0; c < 2; ++c)
        #pragma unroll
        for (int j = 0; j < 8; ++j)
            hv[c][j] = (short)f2bf(tile[c4 + c * 8 + j][r]);
    u16* th = T + (size_t)(nb + r) * En + kb + c4;   // K == En for both weights
    *(s8v*)th = hv[0]; *(s8v*)(th + 8) = hv[1];
}

// -------- bf16 MFMA GEMM: m97 structure, BK=64, chunk-XOR swizzle, XCD swizzle --------
// 128x128 tile, BK=64 (halves barrier count vs BK=32), linear LDS [128 rows][8 chunks
// of 16B], global_load_lds w16 staging. Bank-conflict fix per rule #21 (both-sides):
// LDS dest stays LINEAR; the 16B-chunk index is XOR-permuted on the GLOBAL SOURCE
// (chg = ch ^ (row&7); per-row permutation keeps the 8 lanes of a row inside one
// 128B segment -> coalescing intact) and the SAME XOR is applied on the frag read
// (chunk = (half*4+lg) ^ (row&7) -> 8 distinct banks per 16-lane phase, 2-way free).
// A and B share the per-lane k order -> MFMA's 32-slot dot is exact (bit-identical
// accumulation order to BK=32: half 0 = k 0..31, half 1 = k 32..63).
// XCD swizzle: contiguous work-id chunk per XCD -> A-panel L2 reuse.
// QPRE: scale output cols < En by QSCALE_F before the bf16 round (Q prescale).
template <bool OUT_BF16, bool QPRE>
__global__ __launch_bounds__(256) void gemm_bf16(
    const u16* __restrict__ A, int lda,
    const u16* __restrict__ BT, int ldb,
    float* __restrict__ C, u16* __restrict__ Cb, int ldc,
    const float* __restrict__ bias, int K)
{
    __shared__ __align__(16) u16 As[128 * 64];   // 16 KiB, linear [row][64k]
    __shared__ __align__(16) u16 Bs[128 * 64];   // 16 KiB

    const int t    = threadIdx.x;
    const int lane = t & 63;
    const int w    = t >> 6;
    const int l15  = lane & 15;
    const int lg   = lane >> 4;
    const int wr   = w >> 1;              // 0..1
    const int wc   = w & 1;               // 0..1

    // XCD swizzle: hw id -> work id (bijective, nwg % 8 == 0)
    const int gx  = gridDim.x;
    const int nwg = gx * gridDim.y;
    const int bid = blockIdx.y * gx + blockIdx.x;
    const int swz = (bid & 7) * (nwg >> 3) + (bid >> 3);
    const int m0  = (swz / gx) * 128;
    const int n0  = (swz % gx) * 128;

    f4v acc[4][4];
    #pragma unroll
    for (int m = 0; m < 4; ++m)
        #pragma unroll
        for (int n = 0; n < 4; ++n) acc[m][n] = (f4v){0.f, 0.f, 0.f, 0.f};

    for (int k0 = 0; k0 < K; k0 += 64) {
        __syncthreads();                  // prev iter frag reads complete
        // stage A and B tiles: slot s (16B) = row s>>3, chunk s&7;
        // source chunk XOR-permuted so the frag-read XOR lands on logical k order.
        #pragma unroll
        for (int i = 0; i < 4; ++i) {
            const int s   = i * 256 + t;            // per-lane slot
            const int ub  = (i * 256 + w * 64) * 8; // wave-uniform LDS base (u16)
            const int row = s >> 3;
            const int chg = (s & 7) ^ (row & 7);    // global chunk for this slot
            gload_lds16(A  + (size_t)(m0 + row) * lda + k0 + chg * 8, As + ub);
            gload_lds16(BT + (size_t)(n0 + row) * ldb + k0 + chg * 8, Bs + ub);
        }
        __syncthreads();                  // drains vmcnt: tiles staged

        #pragma unroll
        for (int half = 0; half < 2; ++half) {
            s8v fa[4], fb[4];
            #pragma unroll
            for (int m = 0; m < 4; ++m) {
                const int ra = wr * 64 + m * 16 + l15;
                const int ca = ((half << 2) | lg) ^ (ra & 7);
                fa[m] = *(const s8v*)&As[ra * 64 + ca * 8];
            }
            #pragma unroll
            for (int n = 0; n < 4; ++n) {
                const int rb = wc * 64 + n * 16 + l15;
                const int cb = ((half << 2) | lg) ^ (rb & 7);
                fb[n] = *(const s8v*)&Bs[rb * 64 + cb * 8];
            }
            #pragma unroll
            for (int m = 0; m < 4; ++m)
                #pragma unroll
                for (int n = 0; n < 4; ++n)
                    acc[m][n] = __builtin_amdgcn_mfma_f32_16x16x32_bf16(fa[m], fb[n], acc[m][n], 0, 0, 0);
        }
    }

    if (OUT_BF16) {
        #pragma unroll
        for (int m = 0; m < 4; ++m)
            #pragma unroll
            for (int n = 0; n < 4; ++n) {
                const int col = n0 + wc * 64 + n * 16 + l15;
                const float sc = (QPRE && col < En) ? QSCALE_F : 1.0f;
                #pragma unroll
                for (int r = 0; r < 4; ++r) {
                    const size_t row = m0 + wr * 64 + m * 16 + lg * 4 + r;
                    Cb[row * ldc + col] = f2bf(acc[m][n][r] * sc);
                }
            }
    } else {
        #pragma unroll
        for (int n = 0; n < 4; ++n) {
            const int col = n0 + wc * 64 + n * 16 + l15;
            const float bv = bias[col];
            #pragma unroll
            for (int m = 0; m < 4; ++m)
                #pragma unroll
                for (int r = 0; r < 4; ++r) {
                    const size_t row = m0 + wr * 64 + m * 16 + lg * 4 + r;
                    C[row * ldc + col] = acc[m][n][r] + bv;
                }
        }
    }
}

// ---------------- bf16 MFMA flash attention (R12-exact, measured best 89.3us) ---------
// 8 waves x 32 q = 256 q/block; grid 64 x 8 = 512 blocks. K staged by waves 0-3,
// V by waves 4-7. Swapped QK^T keeps P in registers; fixed-max softmax (Q prescaled
// by log2e/32 -> P = v_exp_f32(S)); O bf16 in-place over the Q region. Pad-68:
// conflict-free frag reads.
__global__ __launch_bounds__(512) void flash_bf16(u16* __restrict__ qkv)
{
    __shared__ __align__(16) u16 lds[8704];   // 17 KiB
    u16* Ks = lds;                            // [64 kv][68 d]
    u16* Vt = lds + 4352;                     // [64 d][68 kv]

    const int t    = threadIdx.x;
    const int lane = t & 63;
    const int w    = t >> 6;                  // 0..7
    const int l15  = lane & 15;
    const int lg   = lane >> 4;

    const int bh = blockIdx.x;
    const int b  = bh >> 4;
    const int h  = bh & 15;
    const int q0 = blockIdx.y * 256;

    const size_t rowB = (size_t)b * Ln;

    // Q fragments (B-operand: lane l15 = q row) in registers for the whole kernel
    s8v qf[2][2];
    #pragma unroll
    for (int qb = 0; qb < 2; ++qb) {
        const size_t qrow = (rowB + q0 + w * 32 + qb * 16 + l15) * QKV_N + h * Dn;
        qf[qb][0] = ldfrag(qkv + qrow + lg * 4);
        qf[qb][1] = ldfrag(qkv + qrow + 32 + lg * 4);
    }

    f4v o[2][4];
    float lpart[2] = {0.f, 0.f};
    #pragma unroll
    for (int qb = 0; qb < 2; ++qb)
        #pragma unroll
        for (int db = 0; db < 4; ++db) o[qb][db] = (f4v){0.f, 0.f, 0.f, 0.f};

    // staging roles: waves 0-3 stage K, waves 4-7 stage V (32B/thread patterns)
    const bool isK = (w < 4);
    const int t4   = t & 255;                  // index within the 256-thread half
    const int sr   = t4 >> 2;                  // K: kv row 0..63
    const int sc   = (t4 & 3) * 16;            // K: d 0,16,32,48
    const int vr   = (t4 >> 6) * 16 + (t4 & 7) * 2;  // V: kv pair base (even)
    const int vc   = ((t4 >> 3) & 7) * 8;            // V: d chunk 0..56

    for (int k0 = 0; k0 < Ln; k0 += 64) {
        s8v x0, x1;
        if (isK) {   // K: 16+16 d-values of kv row sr
            const size_t krow = (rowB + k0 + sr) * QKV_N + En + h * Dn + sc;
            x0 = *(const s8v*)(qkv + krow);
            x1 = *(const s8v*)(qkv + krow + 8);
        } else {     // V: d-chunk vc of kv rows vr, vr+1
            const u16* vp = qkv + (rowB + k0 + vr) * QKV_N + 2 * En + h * Dn + vc;
            x0 = *(const s8v*)vp;
            x1 = *(const s8v*)(vp + QKV_N);
        }

        __syncthreads();                 // prev tile LDS reads complete
        if (isK) {
            *(s8v*)&Ks[sr * 68 + sc]     = x0;
            *(s8v*)&Ks[sr * 68 + sc + 8] = x1;
        } else {
            #pragma unroll
            for (int i = 0; i < 8; ++i) {    // packed dword store: 16 banks/phase
                u32 dw = (u32)(u16)x0[i] | ((u32)(u16)x1[i] << 16);
                *(u32*)&Vt[(vc + i) * 68 + vr] = dw;
            }
        }
        __syncthreads();                 // tile staged

        // ---- S^T = K Q^T : lane l15 = q, reg r + lg = kv (Q carries log2e/32) ----
        f4v st[2][4];
        __builtin_amdgcn_s_setprio(1);
        #pragma unroll
        for (int c = 0; c < 4; ++c) {
            s8v kf0 = ldfrag(&Ks[(c * 16 + l15) * 68 + lg * 4]);
            s8v kf1 = ldfrag(&Ks[(c * 16 + l15) * 68 + 32 + lg * 4]);
            #pragma unroll
            for (int qb = 0; qb < 2; ++qb) {
                f4v acc = (f4v){0.f, 0.f, 0.f, 0.f};
                acc = __builtin_amdgcn_mfma_f32_16x16x32_bf16(kf0, qf[qb][0], acc, 0, 0, 0);
                acc = __builtin_amdgcn_mfma_f32_16x16x32_bf16(kf1, qf[qb][1], acc, 0, 0, 0);
                st[qb][c] = acc;
            }
        }
        __builtin_amdgcn_s_setprio(0);

        // ---- P = v_exp_f32(S) in-register; RNE pack via v_cvt_pk_bf16_f32 ----
        s8v pa[2][2];
        #pragma unroll
        for (int qb = 0; qb < 2; ++qb) {
            float p[4][4];
            #pragma unroll
            for (int c = 0; c < 4; ++c)
                #pragma unroll
                for (int r = 0; r < 4; ++r)
                    p[c][r] = __builtin_amdgcn_exp2f(st[qb][c][r]);
            float s0 = (p[0][0] + p[0][1]) + (p[0][2] + p[0][3]);
            float s1 = (p[1][0] + p[1][1]) + (p[1][2] + p[1][3]);
            float s2 = (p[2][0] + p[2][1]) + (p[2][2] + p[2][3]);
            float s3 = (p[3][0] + p[3][1]) + (p[3][2] + p[3][3]);
            lpart[qb] += (s0 + s1) + (s2 + s3);
            union { s8v s; u32 u[4]; } a0, a1;
            a0.u[0] = cvtpk(p[0][0], p[0][1]);   // kv slots r=0,1   (c=0)
            a0.u[1] = cvtpk(p[0][2], p[0][3]);
            a0.u[2] = cvtpk(p[1][0], p[1][1]);   // kv 16+ (c=1)
            a0.u[3] = cvtpk(p[1][2], p[1][3]);
            a1.u[0] = cvtpk(p[2][0], p[2][1]);   // kv 32+ (c=2)
            a1.u[1] = cvtpk(p[2][2], p[2][3]);
            a1.u[2] = cvtpk(p[3][0], p[3][1]);   // kv 48+ (c=3)
            a1.u[3] = cvtpk(p[3][2], p[3][3]);
            pa[qb][0] = a0.s;
            pa[qb][1] = a1.s;
        }

        // ---- O += P V : A = pa (lane l15 = q), B = Vt rows d ----
        __builtin_amdgcn_s_setprio(1);
        #pragma unroll
        for (int db = 0; db < 4; ++db) {
            s8v vf0 = ldfrag(&Vt[(db * 16 + l15) * 68 + lg * 4]);
            s8v vf1 = ldfrag(&Vt[(db * 16 + l15) * 68 + 32 + lg * 4]);
            #pragma unroll
            for (int qb = 0; qb < 2; ++qb) {
                f4v acc = o[qb][db];
                acc = __builtin_amdgcn_mfma_f32_16x16x32_bf16(pa[qb][0], vf0, acc, 0, 0, 0);
                acc = __builtin_amdgcn_mfma_f32_16x16x32_bf16(pa[qb][1], vf1, acc, 0, 0, 0);
                o[qb][db] = acc;
            }
        }
        __builtin_amdgcn_s_setprio(0);
    }

    // ---- row-sums: lane(l15=q, lg) holds partial over its kv slots; reduce over lg ----
    #pragma unroll
    for (int qb = 0; qb < 2; ++qb) {
        lpart[qb] += __shfl_xor(lpart[qb], 16);
        lpart[qb] += __shfl_xor(lpart[qb], 32);
    }
    __syncthreads();                     // all waves done with K/V LDS reads
    float* sred = (float*)lds;           // [256] row-sums, q-indexed
    if (lg == 0) {
        sred[w * 32 + l15]      = lpart[0];
        sred[w * 32 + 16 + l15] = lpart[1];
    }
    __syncthreads();

    // ---- normalize and write O bf16 over the Q region (q = lg*4+r rows) ----
    #pragma unroll
    for (int qb = 0; qb < 2; ++qb) {
        float inv[4];
        #pragma unroll
        for (int r = 0; r < 4; ++r)
            inv[r] = 1.0f / sred[w * 32 + qb * 16 + lg * 4 + r];
        #pragma unroll
        for (int db = 0; db < 4; ++db)
            #pragma unroll
            for (int r = 0; r < 4; ++r) {
                const size_t idx =
                    (rowB + q0 + w * 32 + qb * 16 + lg * 4 + r) * QKV_N + h * Dn + db * 16 + l15;
                qkv[idx] = f2bf(o[qb][db][r] * inv[r]);
            }
    }
}

extern "C" void kernel_launch(void* const* d_in, const int* in_sizes, int n_in,
                              void* d_out, int out_size, void* d_ws, size_t ws_size,
                              hipStream_t stream)
{
    const float* x      = (const float*)d_in[0];   // [B,L,E]
    const float* w_qkv  = (const float*)d_in[1];   // [E,3E]
    const float* w_proj = (const float*)d_in[2];   // [E,E]
    const float* b_proj = (const float*)d_in[3];   // [E]
    float* out = (float*)d_out;                    // [B,L,E]

    u16* xb  = (u16*)d_ws;                         // [M,E]   16.8 MB
    u16* qkv = xb  + (size_t)Mn * En;              // [M,3E]  50.3 MB
    u16* wqT = qkv + (size_t)Mn * QKV_N;           // [3E,E]   6.3 MB
    u16* wpT = wqT + (size_t)QKV_N * En;           // [E,E]    2.1 MB

    // 0) fused prep: convert x, transpose+convert both weights (one launch)
    prep<<<5120, 256, 0, stream>>>(x, xb, w_qkv, wqT, w_proj, wpT);

    // 1) qkv = x @ w_qkv  (bf16 out; Q cols prescaled by log2e/32; XCD swizzle)
    gemm_bf16<true, true><<<dim3(QKV_N / 128, Mn / 128), 256, 0, stream>>>(
        xb, En, wqT, En, nullptr, qkv, QKV_N, nullptr, En);

    // 2) flash attention; O written bf16 over the Q region (R12-exact)
    flash_bf16<<<dim3(Bn * Hn, Ln / 256), 512, 0, stream>>>(qkv);

    // 3) out = O @ w_proj + b_proj  (fp32 out; XCD swizzle)
    gemm_bf16<false, false><<<dim3(En / 128, Mn / 128), 256, 0, stream>>>(
        qkv, QKV_N, wpT, En, out, nullptr, En, b_proj, En);
}